// Round 13
// baseline (1071.112 us; speedup 1.0000x reference)
//
#include <hip/hip_runtime.h>
#include <float.h>

// VQ-VAE EMA vector quantizer, MI355X (gfx950).
// inputs:  [16,64,64,64] f32 (b,c,h,w) -> N=65536 positions, d=64
// embedding: [64,1024] f32 (d,K)
// outputs (flat, f32): q_st[4194304], loss[1], indices[65536],
//                      new_embedding[65536], new_cluster_size[1024], new_embed_avg[65536]
//
// Lessons: R7  — cooperative grid.sync ~30-40us each; separate launches win.
//          R8/R11 — score plateau ~127us (VALU-f32, LDS-operand-bound, 8 waves/CU);
//                   both fused-kt (150us) and 16x8@128thr (149us) regress.
//          R10 — cross-block ticket + device fences = 9x regression. Never.
//          R12 — infra flake (Trio nursery); resubmitting identical structure.
// R13 == R12: R9 score/finalize + tail trim: dw_accum+ema2 fused (one wave per
// code, no dwT array/atomics/init). 6 dispatches, 0 memsets.

#define K 1024
#define D 64
#define NPOS 65536
#define NELEM 4194304
#define DECAYF 0.99f
#define OMDF 0.01f
#define EPSF 1e-5f
#define CCOST 0.25f

#define OFF_Q 0
#define OFF_LOSS 4194304
#define OFF_IDX 4194305
#define OFF_EMB 4259841
#define OFF_NCS 4325377
#define OFF_AVG 4326401

// ws float layout:
// [0] loss | [64..1088) e2 | [1088..2112) cs | [2112..3137) bstart(int,1025)
// [3200..4224) cursor(int) | [4224..5248) hist(int) | [5248..70784) idxi(int)
// [70784..136320) perm(u32) | [136320..267392) keys(u64 x 65536)
// [267392..332928) ET[K][64] | [332928..) xT[n][64] (optional, 16 MB)

// Tile-transpose E -> ET[K][64], fused e2; init keys/hist/loss (no memsets).
__global__ void __launch_bounds__(256) prep_kernel(
    const float* __restrict__ E, float* __restrict__ ET, float* __restrict__ e2,
    unsigned long long* __restrict__ keys, int* __restrict__ hist,
    float* __restrict__ loss) {
    __shared__ float tile[64][65];
    __shared__ float part[4][64];
    int tid = threadIdx.x;
    int gid = blockIdx.x * 256 + tid;  // 0..4095
#pragma unroll
    for (int i = 0; i < 16; ++i) keys[i * 4096 + gid] = ~0ull;
    if (gid < K) hist[gid] = 0;
    if (gid == 0) *loss = 0.f;

    int k0 = blockIdx.x * 64;
    int kl = tid & 63;
    int cg_ = tid >> 6;  // 0..3
#pragma unroll
    for (int cc = 0; cc < 16; ++cc) {
        int c = cc * 4 + cg_;
        tile[c][kl] = E[c * K + k0 + kl];  // coalesced
    }
    __syncthreads();
    float s = 0.f;
#pragma unroll
    for (int i = 0; i < 16; ++i) {
        float v = tile[cg_ * 16 + i][kl];
        s = fmaf(v, v, s);
    }
    part[cg_][kl] = s;
#pragma unroll
    for (int i = 0; i < 16; ++i) {
        int w = i * 256 + tid;
        int k = w >> 6, c = w & 63;
        ET[(size_t)(k0 + k) * 64 + c] = tile[c][k];
    }
    __syncthreads();
    if (tid < 64) e2[k0 + tid] = part[0][tid] + part[1][tid] + part[2][tid] + part[3][tid];
}

__device__ __forceinline__ unsigned mono_f32(float s) {
    unsigned u = __float_as_uint(s);
    return (u & 0x80000000u) ? ~u : (u | 0x80000000u);
}

// R6/R9-proven: tile 128 pos x 128 codes, grid (8 kt, 512 pt), 256 threads.
__global__ void __launch_bounds__(256, 2) score_kernel(
    const float* __restrict__ in, const float* __restrict__ E,
    const float* __restrict__ e2, unsigned long long* __restrict__ keys) {
    __shared__ __align__(16) float xs[64 * 128];  // [c][pos]
    __shared__ __align__(16) float es[64 * 128];  // [c][code]
    __shared__ float e2s[128];
    unsigned long long* cand = (unsigned long long*)xs;  // reuse: [128 pos][stride 17]

    int tid = threadIdx.x;
    int kt = blockIdx.x;  // 0..7
    int pt = blockIdx.y;  // 0..511
    int n0 = pt * 128;
    int b = n0 >> 12;
    int r0 = n0 & 4095;

    {
        int p4 = (tid & 31) * 4;
        int c0 = tid >> 5;
#pragma unroll
        for (int cc = 0; cc < 64; cc += 8) {
            int c = cc + c0;
            float4 xv = *(const float4*)(in + (size_t)b * 262144 + c * 4096 + r0 + p4);
            *(float4*)(xs + c * 128 + p4) = xv;
            float4 ev = *(const float4*)(E + c * 1024 + kt * 128 + p4);
            *(float4*)(es + c * 128 + p4) = ev;
        }
        if (tid < 128) e2s[tid] = e2[kt * 128 + tid];
    }
    __syncthreads();

    int tx = tid & 15;
    int ty = tid >> 4;
    float acc[8][8];
#pragma unroll
    for (int i = 0; i < 8; ++i)
#pragma unroll
        for (int j = 0; j < 8; ++j) acc[i][j] = 0.f;

#pragma unroll 4
    for (int c = 0; c < 64; ++c) {
        float4 xa0 = *(float4*)(xs + c * 128 + ty * 8);
        float4 xa1 = *(float4*)(xs + c * 128 + ty * 8 + 4);
        float4 eb0 = *(float4*)(es + c * 128 + tx * 4);
        float4 eb1 = *(float4*)(es + c * 128 + 64 + tx * 4);
        float xv[8] = {xa0.x, xa0.y, xa0.z, xa0.w, xa1.x, xa1.y, xa1.z, xa1.w};
        float ev[8] = {eb0.x, eb0.y, eb0.z, eb0.w, eb1.x, eb1.y, eb1.z, eb1.w};
#pragma unroll
        for (int i = 0; i < 8; ++i)
#pragma unroll
            for (int j = 0; j < 8; ++j)
                acc[i][j] = fmaf(xv[i], ev[j], acc[i][j]);
    }
    __syncthreads();

#pragma unroll
    for (int i = 0; i < 8; ++i) {
        float best = FLT_MAX;
        int bk = 0;
#pragma unroll
        for (int j = 0; j < 8; ++j) {
            int kl = (j < 4) ? (tx * 4 + j) : (64 + tx * 4 + (j - 4));  // ascending k
            float s = fmaf(-2.f, acc[i][j], e2s[kl]);
            if (s < best) { best = s; bk = kl; }  // strict <: first min wins
        }
        unsigned long long cd =
            ((unsigned long long)mono_f32(best) << 32) | (unsigned)(kt * 128 + bk);
        cand[(ty * 8 + i) * 17 + tx] = cd;
    }
    __syncthreads();

    if (tid < 128) {
        unsigned long long bc = cand[tid * 17];
#pragma unroll
        for (int t = 1; t < 16; ++t) {
            unsigned long long v = cand[tid * 17 + t];
            if (v < bc) bc = v;
        }
        atomicMin(&keys[n0 + tid], bc);
    }
}

// 4 positions x 8 channels per thread; ET-based q gather; fused hist + idx.
__global__ void __launch_bounds__(256) finalize_kernel(
    const float* __restrict__ in, const float* __restrict__ ET,
    const unsigned long long* __restrict__ keys, float* __restrict__ out,
    int* __restrict__ idxi, float* __restrict__ xT, float* __restrict__ loss,
    int* __restrict__ hist) {
    int tid = threadIdx.x;
    int pg = tid & 31;
    int ch8 = tid >> 5;  // 0..7
    int np = blockIdx.x * 128 + pg * 4;
    int b = np >> 12, r = np & 4095;
    int c0 = ch8 * 8;
    const float* inb = in + (size_t)b * 262144 + r;
    float* qb = out + OFF_Q + (size_t)b * 262144 + r;

    int kk[4];
#pragma unroll
    for (int p = 0; p < 4; ++p) kk[p] = (int)(keys[np + p] & 0x3FFull);

    float4 xv[8];
#pragma unroll
    for (int i = 0; i < 8; ++i) xv[i] = *(const float4*)(inb + (c0 + i) * 4096);

    float4 e0[4], e1[4];
#pragma unroll
    for (int p = 0; p < 4; ++p) {
        const float* ep = ET + (size_t)kk[p] * 64 + c0;
        e0[p] = *(const float4*)ep;
        e1[p] = *(const float4*)(ep + 4);
    }

#define ECOMP(p, i) ((i) < 4 ? ((const float*)&e0[p])[(i)] : ((const float*)&e1[p])[(i) - 4])
#define XCOMP(i, p) ((p) == 0 ? xv[i].x : (p) == 1 ? xv[i].y : (p) == 2 ? xv[i].z : xv[i].w)

    float sq = 0.f;
#pragma unroll
    for (int i = 0; i < 8; ++i) {
        float4 qv = make_float4(ECOMP(0, i), ECOMP(1, i), ECOMP(2, i), ECOMP(3, i));
        *(float4*)(qb + (c0 + i) * 4096) = qv;
        float d0 = qv.x - xv[i].x, d1 = qv.y - xv[i].y;
        float d2 = qv.z - xv[i].z, d3 = qv.w - xv[i].w;
        sq = fmaf(d0, d0, sq); sq = fmaf(d1, d1, sq);
        sq = fmaf(d2, d2, sq); sq = fmaf(d3, d3, sq);
    }

    if (xT) {
#pragma unroll
        for (int p = 0; p < 4; ++p) {
            float* xp = xT + (size_t)(np + p) * 64 + c0;
            *(float4*)xp = make_float4(XCOMP(0, p), XCOMP(1, p), XCOMP(2, p), XCOMP(3, p));
            *(float4*)(xp + 4) = make_float4(XCOMP(4, p), XCOMP(5, p), XCOMP(6, p), XCOMP(7, p));
        }
    }

    if (ch8 == 0) {
#pragma unroll
        for (int p = 0; p < 4; ++p) out[OFF_IDX + np + p] = (float)kk[p];
        *(int4*)(idxi + np) = make_int4(kk[0], kk[1], kk[2], kk[3]);
#pragma unroll
        for (int p = 0; p < 4; ++p) atomicAdd(&hist[kk[p]], 1);
    }

#pragma unroll
    for (int off = 32; off > 0; off >>= 1) sq += __shfl_down(sq, off);
    if ((tid & 63) == 0) atomicAdd(loss, sq);
}

// One block: exclusive scan of hist (bstart + cursor) + EMA stage1.
__global__ void __launch_bounds__(1024) scan_kernel(
    const int* __restrict__ hist, const float* __restrict__ cluster_size,
    const float* __restrict__ loss, float* __restrict__ out,
    float* __restrict__ cs_ws, int* __restrict__ bstart, int* __restrict__ cursor) {
    int t = threadIdx.x;
    __shared__ int sc[1024];
    __shared__ float fred[1024];
    int cnt = hist[t];
    sc[t] = cnt;
    __syncthreads();
    for (int off = 1; off < 1024; off <<= 1) {
        int v = (t >= off) ? sc[t - off] : 0;
        __syncthreads();
        sc[t] += v;
        __syncthreads();
    }
    int excl = sc[t] - cnt;
    bstart[t] = excl;
    cursor[t] = excl;
    if (t == 0) bstart[1024] = NPOS;

    float ncs = cluster_size[t] * DECAYF + OMDF * (float)cnt;
    fred[t] = ncs;
    __syncthreads();
    for (int s = 512; s > 0; s >>= 1) {
        if (t < s) fred[t] += fred[t + s];
        __syncthreads();
    }
    float nsum = fred[0];
    out[OFF_NCS + t] = ncs;
    cs_ws[t] = (ncs + EPSF) / (nsum + 1024.f * EPSF) * nsum;
    if (t == 0) out[OFF_LOSS] = CCOST * loss[0] / (float)NELEM;
}

__global__ void __launch_bounds__(256) scatter_kernel(
    const int* __restrict__ idxi, int* __restrict__ cursor,
    unsigned* __restrict__ perm) {
    int n = blockIdx.x * 256 + threadIdx.x;
    int k = idxi[n];
    int slot = atomicAdd(&cursor[k], 1);
    perm[slot] = (unsigned)n;
}

// Fused dw + EMA stage2: one WAVE per code (4 codes/block). Coalesced perm
// chunk load + shfl broadcast -> independent 256B row gathers; register
// accumulate; LDS exchange; AVG/EMB writes. No dwT array, no atomics.
__global__ void __launch_bounds__(256) dw_ema_kernel(
    const float* __restrict__ in, const float* __restrict__ xT,
    const unsigned* __restrict__ perm, const int* __restrict__ bstart,
    const float* __restrict__ embed_avg, const float* __restrict__ cs_ws,
    float* __restrict__ out) {
    int tid = threadIdx.x;
    int c = tid & 63;
    int wv = tid >> 6;
    int k0 = blockIdx.x * 4;
    int k = k0 + wv;
    int s0 = bstart[k], s1 = bstart[k + 1];

    float acc = 0.f;
    for (int base = s0; base < s1; base += 64) {
        unsigned v = 0;
        if (base + c < s1) v = perm[base + c];  // coalesced
        int cnt = min(64, s1 - base);
        for (int i = 0; i < cnt; ++i) {
            unsigned n = __shfl(v, i);  // broadcast -> wave reads one 256B row
            if (xT) acc += xT[(size_t)n * 64 + c];
            else acc += in[(size_t)(n >> 12) * 262144 + c * 4096 + (n & 4095)];
        }
    }

    __shared__ float dwb[4][64];
    dwb[wv][c] = acc;
    __syncthreads();
    if (tid < 64) {
        int cc = tid;
        float4 ea = *(const float4*)(embed_avg + (size_t)cc * K + k0);  // k0%4==0
        float4 cs4 = *(const float4*)(cs_ws + k0);
        float a0 = ea.x * DECAYF + OMDF * dwb[0][cc];
        float a1 = ea.y * DECAYF + OMDF * dwb[1][cc];
        float a2 = ea.z * DECAYF + OMDF * dwb[2][cc];
        float a3 = ea.w * DECAYF + OMDF * dwb[3][cc];
        size_t o = (size_t)cc * K + k0;
        out[OFF_AVG + o] = a0;     out[OFF_AVG + o + 1] = a1;  // OFF_AVG odd: scalar
        out[OFF_AVG + o + 2] = a2; out[OFF_AVG + o + 3] = a3;
        out[OFF_EMB + o] = a0 / cs4.x;     out[OFF_EMB + o + 1] = a1 / cs4.y;
        out[OFF_EMB + o + 2] = a2 / cs4.z; out[OFF_EMB + o + 3] = a3 / cs4.w;
    }
}

extern "C" void kernel_launch(void* const* d_in, const int* in_sizes, int n_in,
                              void* d_out, int out_size, void* d_ws, size_t ws_size,
                              hipStream_t stream) {
    const float* in = (const float*)d_in[0];
    const float* E = (const float*)d_in[1];
    const float* cluster_size = (const float*)d_in[2];
    const float* embed_avg = (const float*)d_in[3];
    float* out = (float*)d_out;
    float* ws = (float*)d_ws;

    float* loss = ws;
    float* e2 = ws + 64;
    float* cs = ws + 1088;
    int* bstart = (int*)(ws + 2112);    // 1025
    int* cursor = (int*)(ws + 3200);    // 1024
    int* hist = (int*)(ws + 4224);      // 1024
    int* idxi = (int*)(ws + 5248);      // 65536
    unsigned* perm = (unsigned*)(ws + 70784);  // 65536
    unsigned long long* keys = (unsigned long long*)(ws + 136320);  // 65536 u64
    float* ET = ws + 267392;            // 65536 ([K][64])
    float* xT = (ws_size >= (332928ull + 4194304ull) * 4ull) ? (ws + 332928) : nullptr;

    prep_kernel<<<K / 64, 256, 0, stream>>>(E, ET, e2, keys, hist, loss);
    score_kernel<<<dim3(8, 512), 256, 0, stream>>>(in, E, e2, keys);
    finalize_kernel<<<NPOS / 128, 256, 0, stream>>>(in, ET, keys, out, idxi, xT, loss, hist);
    scan_kernel<<<1, 1024, 0, stream>>>(hist, cluster_size, loss, out, cs, bstart, cursor);
    scatter_kernel<<<NPOS / 256, 256, 0, stream>>>(idxi, cursor, perm);
    dw_ema_kernel<<<K / 4, 256, 0, stream>>>(in, xT, perm, bstart, embed_avg, cs, out);
}

// Round 14
// 288.630 us; speedup vs baseline: 3.7110x; 3.7110x over previous
//
#include <hip/hip_runtime.h>
#include <float.h>

// VQ-VAE EMA vector quantizer, MI355X (gfx950).
// inputs:  [16,64,64,64] f32 (b,c,h,w) -> N=65536 positions, d=64
// embedding: [64,1024] f32 (d,K)
// outputs (flat, f32): q_st[4194304], loss[1], indices[65536],
//                      new_embedding[65536], new_cluster_size[1024], new_embed_avg[65536]
//
// Lessons: R7  — cooperative grid.sync ~30-40us each; separate launches win.
//          R8/R11 — score plateau ~127us (VALU-f32, LDS-operand-bound, 8 waves/CU).
//          R10 — cross-block ticket + device fences = 9x regression. Never.
//          R13 — bucket sizes are HEAVILY SKEWED: per-code work assignment
//                (block/code or wave/code) = 350-805us serial straggler.
//                Balanced 32-sorted-entries/wave + dwT atomics is the only
//                dw structure that works. Do not retry per-code.
// R14 == R9 exactly (proven 289us): 7 dispatches, 0 memsets.

#define K 1024
#define D 64
#define NPOS 65536
#define NELEM 4194304
#define DECAYF 0.99f
#define OMDF 0.01f
#define EPSF 1e-5f
#define CCOST 0.25f

#define OFF_Q 0
#define OFF_LOSS 4194304
#define OFF_IDX 4194305
#define OFF_EMB 4259841
#define OFF_NCS 4325377
#define OFF_AVG 4326401

// ws float layout:
// [0] loss | [64..1088) e2 | [1088..2112) cs | [2112..3136) cursor(int)
// [3136..4160) hist(int) | [4224..69760) idxi(int) | [69760..135296) perm(u32)
// [135296..266368) keys(u64 x 65536) | [266368..331904) dwT[K][64]
// [331904..397440) ET[K][64] | [397440..) xT[n][64] (optional, 16 MB)

// Tile-transpose E -> ET[K][64], fused e2; init keys/hist/loss/dwT (no memsets).
__global__ void __launch_bounds__(256) prep_kernel(
    const float* __restrict__ E, float* __restrict__ ET, float* __restrict__ e2,
    unsigned long long* __restrict__ keys, int* __restrict__ hist,
    float* __restrict__ loss, float* __restrict__ dwT) {
    __shared__ float tile[64][65];
    __shared__ float part[4][64];
    int tid = threadIdx.x;
    int gid = blockIdx.x * 256 + tid;  // 0..4095
#pragma unroll
    for (int i = 0; i < 16; ++i) keys[i * 4096 + gid] = ~0ull;
#pragma unroll
    for (int i = 0; i < 16; ++i) dwT[i * 4096 + gid] = 0.f;
    if (gid < K) hist[gid] = 0;
    if (gid == 0) *loss = 0.f;

    int k0 = blockIdx.x * 64;
    int kl = tid & 63;
    int cg_ = tid >> 6;  // 0..3
#pragma unroll
    for (int cc = 0; cc < 16; ++cc) {
        int c = cc * 4 + cg_;
        tile[c][kl] = E[c * K + k0 + kl];  // coalesced
    }
    __syncthreads();
    float s = 0.f;
#pragma unroll
    for (int i = 0; i < 16; ++i) {
        float v = tile[cg_ * 16 + i][kl];
        s = fmaf(v, v, s);
    }
    part[cg_][kl] = s;
#pragma unroll
    for (int i = 0; i < 16; ++i) {
        int w = i * 256 + tid;
        int k = w >> 6, c = w & 63;
        ET[(size_t)(k0 + k) * 64 + c] = tile[c][k];
    }
    __syncthreads();
    if (tid < 64) e2[k0 + tid] = part[0][tid] + part[1][tid] + part[2][tid] + part[3][tid];
}

__device__ __forceinline__ unsigned mono_f32(float s) {
    unsigned u = __float_as_uint(s);
    return (u & 0x80000000u) ? ~u : (u | 0x80000000u);
}

// R6/R9-proven shape: tile 128 pos x 128 codes, grid (8 kt, 512 pt) = 4096 blocks.
__global__ void __launch_bounds__(256, 2) score_kernel(
    const float* __restrict__ in, const float* __restrict__ E,
    const float* __restrict__ e2, unsigned long long* __restrict__ keys) {
    __shared__ __align__(16) float xs[64 * 128];  // [c][pos]
    __shared__ __align__(16) float es[64 * 128];  // [c][code]
    __shared__ float e2s[128];
    unsigned long long* cand = (unsigned long long*)xs;  // reuse: [128 pos][stride 17]

    int tid = threadIdx.x;
    int kt = blockIdx.x;  // 0..7
    int pt = blockIdx.y;  // 0..511
    int n0 = pt * 128;
    int b = n0 >> 12;
    int r0 = n0 & 4095;

    {
        int p4 = (tid & 31) * 4;
        int c0 = tid >> 5;
#pragma unroll
        for (int cc = 0; cc < 64; cc += 8) {
            int c = cc + c0;
            float4 xv = *(const float4*)(in + (size_t)b * 262144 + c * 4096 + r0 + p4);
            *(float4*)(xs + c * 128 + p4) = xv;
            float4 ev = *(const float4*)(E + c * 1024 + kt * 128 + p4);
            *(float4*)(es + c * 128 + p4) = ev;
        }
        if (tid < 128) e2s[tid] = e2[kt * 128 + tid];
    }
    __syncthreads();

    int tx = tid & 15;
    int ty = tid >> 4;
    float acc[8][8];
#pragma unroll
    for (int i = 0; i < 8; ++i)
#pragma unroll
        for (int j = 0; j < 8; ++j) acc[i][j] = 0.f;

#pragma unroll 4
    for (int c = 0; c < 64; ++c) {
        float4 xa0 = *(float4*)(xs + c * 128 + ty * 8);
        float4 xa1 = *(float4*)(xs + c * 128 + ty * 8 + 4);
        float4 eb0 = *(float4*)(es + c * 128 + tx * 4);
        float4 eb1 = *(float4*)(es + c * 128 + 64 + tx * 4);
        float xv[8] = {xa0.x, xa0.y, xa0.z, xa0.w, xa1.x, xa1.y, xa1.z, xa1.w};
        float ev[8] = {eb0.x, eb0.y, eb0.z, eb0.w, eb1.x, eb1.y, eb1.z, eb1.w};
#pragma unroll
        for (int i = 0; i < 8; ++i)
#pragma unroll
            for (int j = 0; j < 8; ++j)
                acc[i][j] = fmaf(xv[i], ev[j], acc[i][j]);
    }
    __syncthreads();

#pragma unroll
    for (int i = 0; i < 8; ++i) {
        float best = FLT_MAX;
        int bk = 0;
#pragma unroll
        for (int j = 0; j < 8; ++j) {
            int kl = (j < 4) ? (tx * 4 + j) : (64 + tx * 4 + (j - 4));  // ascending k
            float s = fmaf(-2.f, acc[i][j], e2s[kl]);
            if (s < best) { best = s; bk = kl; }  // strict <: first min wins
        }
        unsigned long long cd =
            ((unsigned long long)mono_f32(best) << 32) | (unsigned)(kt * 128 + bk);
        cand[(ty * 8 + i) * 17 + tx] = cd;
    }
    __syncthreads();

    if (tid < 128) {
        unsigned long long bc = cand[tid * 17];
#pragma unroll
        for (int t = 1; t < 16; ++t) {
            unsigned long long v = cand[tid * 17 + t];
            if (v < bc) bc = v;
        }
        atomicMin(&keys[n0 + tid], bc);
    }
}

// 4 positions x 8 channels per thread; ET-based q gather; fused hist + idx.
__global__ void __launch_bounds__(256) finalize_kernel(
    const float* __restrict__ in, const float* __restrict__ ET,
    const unsigned long long* __restrict__ keys, float* __restrict__ out,
    int* __restrict__ idxi, float* __restrict__ xT, float* __restrict__ loss,
    int* __restrict__ hist) {
    int tid = threadIdx.x;
    int pg = tid & 31;
    int ch8 = tid >> 5;  // 0..7
    int np = blockIdx.x * 128 + pg * 4;
    int b = np >> 12, r = np & 4095;
    int c0 = ch8 * 8;
    const float* inb = in + (size_t)b * 262144 + r;
    float* qb = out + OFF_Q + (size_t)b * 262144 + r;

    int kk[4];
#pragma unroll
    for (int p = 0; p < 4; ++p) kk[p] = (int)(keys[np + p] & 0x3FFull);

    float4 xv[8];
#pragma unroll
    for (int i = 0; i < 8; ++i) xv[i] = *(const float4*)(inb + (c0 + i) * 4096);

    float4 e0[4], e1[4];
#pragma unroll
    for (int p = 0; p < 4; ++p) {
        const float* ep = ET + (size_t)kk[p] * 64 + c0;
        e0[p] = *(const float4*)ep;
        e1[p] = *(const float4*)(ep + 4);
    }

#define ECOMP(p, i) ((i) < 4 ? ((const float*)&e0[p])[(i)] : ((const float*)&e1[p])[(i) - 4])
#define XCOMP(i, p) ((p) == 0 ? xv[i].x : (p) == 1 ? xv[i].y : (p) == 2 ? xv[i].z : xv[i].w)

    float sq = 0.f;
#pragma unroll
    for (int i = 0; i < 8; ++i) {
        float4 qv = make_float4(ECOMP(0, i), ECOMP(1, i), ECOMP(2, i), ECOMP(3, i));
        *(float4*)(qb + (c0 + i) * 4096) = qv;
        float d0 = qv.x - xv[i].x, d1 = qv.y - xv[i].y;
        float d2 = qv.z - xv[i].z, d3 = qv.w - xv[i].w;
        sq = fmaf(d0, d0, sq); sq = fmaf(d1, d1, sq);
        sq = fmaf(d2, d2, sq); sq = fmaf(d3, d3, sq);
    }

    if (xT) {
#pragma unroll
        for (int p = 0; p < 4; ++p) {
            float* xp = xT + (size_t)(np + p) * 64 + c0;
            *(float4*)xp = make_float4(XCOMP(0, p), XCOMP(1, p), XCOMP(2, p), XCOMP(3, p));
            *(float4*)(xp + 4) = make_float4(XCOMP(4, p), XCOMP(5, p), XCOMP(6, p), XCOMP(7, p));
        }
    }

    if (ch8 == 0) {
#pragma unroll
        for (int p = 0; p < 4; ++p) out[OFF_IDX + np + p] = (float)kk[p];
        *(int4*)(idxi + np) = make_int4(kk[0], kk[1], kk[2], kk[3]);
#pragma unroll
        for (int p = 0; p < 4; ++p) atomicAdd(&hist[kk[p]], 1);
    }

#pragma unroll
    for (int off = 32; off > 0; off >>= 1) sq += __shfl_down(sq, off);
    if ((tid & 63) == 0) atomicAdd(loss, sq);
}

// One block: exclusive scan of hist + EMA stage1.
__global__ void __launch_bounds__(1024) scan_kernel(
    const int* __restrict__ hist, const float* __restrict__ cluster_size,
    const float* __restrict__ loss, float* __restrict__ out,
    float* __restrict__ cs_ws, int* __restrict__ cursor) {
    int t = threadIdx.x;
    __shared__ int sc[1024];
    __shared__ float fred[1024];
    int cnt = hist[t];
    sc[t] = cnt;
    __syncthreads();
    for (int off = 1; off < 1024; off <<= 1) {
        int v = (t >= off) ? sc[t - off] : 0;
        __syncthreads();
        sc[t] += v;
        __syncthreads();
    }
    cursor[t] = sc[t] - cnt;

    float ncs = cluster_size[t] * DECAYF + OMDF * (float)cnt;
    fred[t] = ncs;
    __syncthreads();
    for (int s = 512; s > 0; s >>= 1) {
        if (t < s) fred[t] += fred[t + s];
        __syncthreads();
    }
    float nsum = fred[0];
    out[OFF_NCS + t] = ncs;
    cs_ws[t] = (ncs + EPSF) / (nsum + 1024.f * EPSF) * nsum;
    if (t == 0) out[OFF_LOSS] = CCOST * loss[0] / (float)NELEM;
}

__global__ void __launch_bounds__(256) scatter_kernel(
    const int* __restrict__ idxi, int* __restrict__ cursor,
    unsigned* __restrict__ perm) {
    int n = blockIdx.x * 256 + threadIdx.x;
    int k = idxi[n];
    int slot = atomicAdd(&cursor[k], 1);
    perm[slot] = ((unsigned)k << 17) | (unsigned)n;  // k:10b, n:17b
}

// Balanced segmented reduction over sorted perm; wave = 32 entries.
// (R13 lesson: balance beats per-code — bucket skew makes per-code serial.)
__global__ void __launch_bounds__(256) dw_accum_kernel(
    const float* __restrict__ in, const float* __restrict__ xT,
    const unsigned* __restrict__ perm, float* __restrict__ dwT) {
    int t = threadIdx.x;
    int c = t & 63;
    int wv = t >> 6;
    int base = (blockIdx.x * 4 + wv) * 32;  // 2048 waves x 32 = 65536

    __shared__ unsigned spm[4][32];
    if (c < 32) spm[wv][c] = perm[base + c];
    __syncthreads();

    float acc = 0.f;
    unsigned cur = spm[wv][0] >> 17;
#pragma unroll 4
    for (int i = 0; i < 32; ++i) {
        unsigned e = spm[wv][i];  // broadcast
        unsigned k = e >> 17;
        unsigned n = e & 0x1FFFFu;
        if (k != cur) {  // wave-uniform
            atomicAdd(&dwT[cur * 64 + c], acc);
            acc = 0.f;
            cur = k;
        }
        if (xT) {
            acc += xT[(size_t)n * 64 + c];  // 256B contiguous per wave
        } else {
            acc += in[(size_t)(n >> 12) * 262144 + c * 4096 + (n & 4095)];
        }
    }
    atomicAdd(&dwT[cur * 64 + c], acc);
}

__global__ void __launch_bounds__(256) ema2_kernel(
    const float* __restrict__ embed_avg, const float* __restrict__ dwT,
    const float* __restrict__ cs_ws, float* __restrict__ out) {
    int i = blockIdx.x * 256 + threadIdx.x;  // i = c*K + k
    int k = i & (K - 1);
    int c = i >> 10;
    float avg = embed_avg[i] * DECAYF + OMDF * dwT[k * 64 + c];
    out[OFF_AVG + i] = avg;
    out[OFF_EMB + i] = avg / cs_ws[k];
}

extern "C" void kernel_launch(void* const* d_in, const int* in_sizes, int n_in,
                              void* d_out, int out_size, void* d_ws, size_t ws_size,
                              hipStream_t stream) {
    const float* in = (const float*)d_in[0];
    const float* E = (const float*)d_in[1];
    const float* cluster_size = (const float*)d_in[2];
    const float* embed_avg = (const float*)d_in[3];
    float* out = (float*)d_out;
    float* ws = (float*)d_ws;

    float* loss = ws;
    float* e2 = ws + 64;
    float* cs = ws + 1088;
    int* cursor = (int*)(ws + 2112);   // 1024
    int* hist = (int*)(ws + 3136);     // 1024
    int* idxi = (int*)(ws + 4224);     // 65536
    unsigned* perm = (unsigned*)(ws + 69760);  // 65536
    unsigned long long* keys = (unsigned long long*)(ws + 135296);  // 65536 u64
    float* dwT = ws + 266368;          // 65536 ([K][64])
    float* ET = ws + 331904;           // 65536 ([K][64])
    float* xT = (ws_size >= (397440ull + 4194304ull) * 4ull) ? (ws + 397440) : nullptr;

    prep_kernel<<<K / 64, 256, 0, stream>>>(E, ET, e2, keys, hist, loss, dwT);
    score_kernel<<<dim3(8, 512), 256, 0, stream>>>(in, E, e2, keys);
    finalize_kernel<<<NPOS / 128, 256, 0, stream>>>(in, ET, keys, out, idxi, xT, loss, hist);
    scan_kernel<<<1, 1024, 0, stream>>>(hist, cluster_size, loss, out, cs, cursor);
    scatter_kernel<<<NPOS / 256, 256, 0, stream>>>(idxi, cursor, perm);
    dw_accum_kernel<<<512, 256, 0, stream>>>(in, xT, perm, dwT);
    ema2_kernel<<<D * K / 256, 256, 0, stream>>>(embed_avg, dwT, cs, out);
}